// Round 22
// baseline (212.271 us; speedup 1.0000x reference)
//
#include <hip/hip_runtime.h>
#include <math.h>

// SLAYER SNN forward, 6 layers, T=2048.
// Policy: compute near the TRUE value (error << reference's own fp32 noise
// ~1e-5) so binary spike decisions match the golden fp32 reference exactly.
//
// PSP = exact 2nd-order IIR of the truncated SRM kernel; refractory = 2-state
// recurrence; time-chunked speculative scan (64 chunks x 32 steps, 48-step
// warmup -- WUP=48 proven R7; chunks with t0<WUP start at ts=0 EXACTLY).
//
// DENSE1 (1600->300) and CONV2 as EXACT fixed-point bf16 MFMA:
//   w_fixed = round(w*2^45) = sum_{j<6} d_j 256^j, d_j signed 8-bit digits.
//   Digits and 0/1 spikes are exact in bf16; mfma_f32_16x16x32_bf16
//   accumulates integer partial sums -> EXACT in f32 C. Cross-wave reduce in
//   F32 (sums of exact ints -> exact), f64 limb combine.
// R22 dense1: K split across 2 BLOCK-halves (kc) -> grid 512 = 2 blocks/CU
//   (16 waves/CU = 4/SIMD, R18's proven TLP) while keeping R19's 32-row
//   M-tile. Wave = one 16-row subtile x one 7-ks chunk; 4-way f32 reduce
//   (exact, < 2^17) via 43KB LDS. Halves write disjoint f64 zpart buffers
//   (exact ints, one writer/element -- no atomics); k_combine1 sums+scales.
//   zpart overlays dead PADY/y2b/s1b (rewritten each replay before dense1).

#define T_BINS 2048
#define K_SRM  100
#define AEXP   0.36787944117144233   // e^-1
#define CHK    32                    // chunk output length
#define WUP    48                    // refractory warmup length (proven R7)
#define NCHK   (T_BINS / CHK)        // 64
#define FIXS   35184372088832.0      // 2^45
#define KSP    56                    // dense1 padded ks count (50 real + 6)

typedef __attribute__((ext_vector_type(8))) short          s16x8;
typedef __attribute__((ext_vector_type(8))) unsigned short u16x8;
typedef __attribute__((ext_vector_type(4))) float          f32x4;

// ---------------- fused prep: conv1 + packB + packB2 + transposes + init ----
__global__ __launch_bounds__(256) void k_prep(
    const float* __restrict__ x, const float* __restrict__ Wc1,
    const float* __restrict__ Wc2, const float* __restrict__ Wf1,
    const float* __restrict__ Wf2, const float* __restrict__ Wf3,
    float* __restrict__ c1, double* __restrict__ Scum, double* __restrict__ H,
    float* __restrict__ WT2, float* __restrict__ WT3,
    unsigned short* __restrict__ BL, unsigned short* __restrict__ BL2) {
  int b = blockIdx.x, tid = threadIdx.x;
  if (b < 19) {                         // ---- conv1 -> c1[4704]
    int idx = b * 256 + tid;
    if (idx >= 4704) return;
    int o = idx / 784, r = idx % 784, i = r / 28, j = r % 28;
    double acc = 0.0;
    for (int ci = 0; ci < 3; ++ci)
      for (int ky = 0; ky < 5; ++ky) {
        const float* xr = x + ci * 1024 + (i + ky) * 32 + j;
        const float* wr = Wc1 + ((o * 3 + ci) * 5 + ky) * 5;
#pragma unroll
        for (int kx = 0; kx < 5; ++kx)
          acc += (double)xr[kx] * (double)wr[kx];
      }
    c1[idx] = (float)acc;
  } else if (b < 299) {                 // ---- packB (dense1): 6 bf16 limbs
    int idx = (b - 19) * 256 + tid;     // 56 ks x 320 n x 4 g = 71680
    if (idx >= KSP * 320 * 4) return;
    int g = idx & 3, rest = idx >> 2;
    int n = rest % 320, ks = rest / 320;
    u16x8 out[6];
#pragma unroll
    for (int j = 0; j < 6; ++j)
#pragma unroll
      for (int jj = 0; jj < 8; ++jj) out[j][jj] = 0;
    if (n < 300 && ks < 50) {
      const float* wr = Wf1 + (size_t)n * 1600 + ks * 32 + g * 8;
#pragma unroll
      for (int jj = 0; jj < 8; ++jj) {
        long long v = llrint((double)wr[jj] * FIXS);
#pragma unroll
        for (int j = 0; j < 6; ++j) {
          int d = (int)(signed char)(v & 0xFF);
          v = (v - d) >> 8;
          float fd = (float)d;               // exact; bf16 truncation exact
          unsigned int fb = __float_as_uint(fd);
          out[j][jj] = (unsigned short)(fb >> 16);
        }
      }
    }
#pragma unroll
    for (int j = 0; j < 6; ++j)
      ((u16x8*)BL)[((j * KSP + ks) * 320 + n) * 4 + g] = out[j];
  } else if (b < 481) {                 // ---- WT2 / WT3 transposes
    int idx = (b - 299) * 256 + tid;
    if (idx < 45000) {
      int c = idx / 150, o = idx - c * 150;
      WT2[idx] = Wf2[o * 300 + c];
    } else if (idx < 46500) {
      int j = idx - 45000, c = j / 10, o = j - c * 10;
      WT3[j] = Wf3[o * 150 + c];
    }
  } else if (b < 483) {                 // ---- packB2 (conv2): 6 bf16 limbs
    int idx = (b - 481) * 256 + tid;    // 5 ks x 16 o x 4 g = 320
    if (idx >= 320) return;
    int g = idx & 3, rest = idx >> 2;
    int o = rest & 15, ks = rest >> 4;  // ks in 0..4
    u16x8 out[6];
#pragma unroll
    for (int j = 0; j < 6; ++j)
#pragma unroll
      for (int jj = 0; jj < 8; ++jj) out[j][jj] = 0;
#pragma unroll
    for (int jj = 0; jj < 8; ++jj) {
      int k = ks * 32 + g * 8 + jj;
      if (k < 150) {
        long long v = llrint((double)Wc2[o * 150 + k] * FIXS);
#pragma unroll
        for (int j = 0; j < 6; ++j) {
          int d = (int)(signed char)(v & 0xFF);
          v = (v - d) >> 8;
          float fd = (float)d;
          unsigned int fb = __float_as_uint(fd);
          out[j][jj] = (unsigned short)(fb >> 16);
        }
      }
    }
#pragma unroll
    for (int j = 0; j < 6; ++j)          // lane-contiguous layout: r fastest
      ((u16x8*)BL2)[((j * 5 + ks) * 4 + g) * 16 + o] = out[j];
  } else {                              // ---- init tables
    if (tid == 0) {
      double acc = 0.0;
      for (int k = 0; k < K_SRM; ++k) {
        double tk = (double)k;
        double h = (tk * 0.1) * exp(1.0 - tk * 0.1);
        H[k] = h; acc += h; Scum[k] = acc;
      }
      H[100] = 0.0; H[101] = 0.0;
    }
  }
}

// ---------------- layer1 chunked scan: p1[t] = c1*Scum[t] -------------------
__global__ __launch_bounds__(256) void k_scan1_chunk(
    const float* __restrict__ c1, const double* __restrict__ Scum_g,
    unsigned char* __restrict__ s1b) {
  __shared__ double Sc[K_SRM];
  for (int k = threadIdx.x; k < K_SRM; k += 256) Sc[k] = Scum_g[k];
  __syncthreads();
  int idx = blockIdx.x * 256 + threadIdx.x;
  int chunk = idx / 4704, n = idx - chunk * 4704;
  int t0 = chunk * CHK;
  int ts = t0 - WUP; if (ts < 0) ts = 0;   // ts==0 -> exact init
  double w = (double)c1[n];
  double e1 = 0.0, e2 = 0.0;
  double u = w * Sc[ts < (K_SRM - 1) ? ts : (K_SRM - 1)];
  unsigned char* outp = s1b + n;
  for (int t = ts; t < t0; ++t) {       // warmup, no store
    double s = (u >= 1.0) ? 1.0 : 0.0;
    int si = t + 1 < (K_SRM - 1) ? t + 1 : (K_SRM - 1);
    u = w * Sc[si] - 2.0 * ((e1 + e2) + s);
    double t1 = e1 + s;
    e2 = AEXP * (e2 + t1); e1 = AEXP * t1;
  }
#pragma unroll 8
  for (int t = t0; t < t0 + CHK; ++t) { // output
    double s = (u >= 1.0) ? 1.0 : 0.0;
    outp[(size_t)t * 4704] = (unsigned char)s;
    int si = t + 1 < (K_SRM - 1) ? t + 1 : (K_SRM - 1);
    u = w * Sc[si] - 2.0 * ((e1 + e2) + s);
    double t1 = e1 + s;
    e2 = AEXP * (e2 + t1); e1 = AEXP * t1;
  }
}

// ---------------- pool: 2x2 spike count -> y2b[t][1176] bytes ---------------
__global__ __launch_bounds__(256) void k_pool(const unsigned char* __restrict__ s1b,
                                              unsigned char* __restrict__ y2b) {
  int idx = blockIdx.x * blockDim.x + threadIdx.x;
  if (idx >= 1176 * T_BINS) return;
  int t = idx / 1176, n2 = idx - t * 1176;
  int c = n2 / 196, r = n2 % 196, i = r / 14, j = r % 14;
  const unsigned char* b = s1b + (size_t)t * 4704 + c * 784 + (2 * i) * 28 + 2 * j;
  y2b[idx] = (unsigned char)((int)b[0] + (int)b[1] + (int)b[28] + (int)b[29]);
}

// ---------------- chunked fused PSP(IIR) + spike scan -----------------------
template <typename Tin, typename Tout>
__global__ __launch_bounds__(256) void k_psp_scan_chunk(
    const Tin* __restrict__ z, Tout* __restrict__ sout, int N,
    long strideT, long strideN, const double* __restrict__ H_g,
    double A1, double A2, double B1, double C0, double C1, double xscale) {
  __shared__ double Hs[102];
  for (int k = threadIdx.x; k < 102; k += 256) Hs[k] = H_g[k];
  __syncthreads();
  int idx = blockIdx.x * blockDim.x + threadIdx.x;
  if (idx >= NCHK * N) return;
  int chunk = idx / N, n = idx - chunk * N;
  int t0 = chunk * CHK;
  int ts = t0 - WUP; if (ts < 0) ts = 0;   // ts==0 -> exact init
  const Tin* zn = z + n;

  // exact IIR init: accA=p[ts], accB=p[ts-1] (100-tap FIR, 10-deep pipe)
  double accA = 0.0, accB = 0.0;
  float fA[10], fB[10];
#define LOADF(BUF, J0)                                               \
  { _Pragma("unroll")                                                \
    for (int q_ = 0; q_ < 10; ++q_)                                  \
      BUF[q_] = (float)zn[(long)(ts - 1 - ((J0) + q_)) * (long)N]; }
#define FMA10(BUF, J0)                                               \
  { _Pragma("unroll")                                                \
    for (int q_ = 0; q_ < 10; ++q_) {                                \
      double v_ = (double)BUF[q_];                                   \
      accA += Hs[(J0) + q_ + 1] * v_;                                \
      accB += Hs[(J0) + q_] * v_;                                    \
    } }
  LOADF(fA, 0)
  for (int q = 0; q < 100; q += 20) {
    LOADF(fB, q + 10)
    FMA10(fA, q)
    LOADF(fA, q + 20)                  // q=80: overshoot, in-bounds, unused
    FMA10(fB, q + 10)
  }
#undef LOADF
#undef FMA10
  double pp1 = accA * xscale;          // p[ts]
  double pp2 = accB * xscale;          // p[ts-1]
  double xm100 = (double)(float)zn[(long)(ts - 100) * (long)N];
  double u = pp1, e1 = 0.0, e2 = 0.0;  // refractory zero (exact at ts==0)

  float cA[8], cB[8], lA[8], lB[8];
  size_t oa = (size_t)n * (size_t)strideN + (size_t)t0 * (size_t)strideT;
  int nwg = (t0 - ts) >> 3;            // 0, 4, or 6 warmup groups
  int ngrp = nwg + CHK / 8;            // 4, 8, or 10 (even)
#define PREF8(CBUF, LBUF, TB)                                        \
  { long tb_ = (long)(TB);                                           \
    _Pragma("unroll")                                                \
    for (int j_ = 0; j_ < 8; ++j_) {                                 \
      CBUF[j_] = (float)zn[(tb_ + j_) * (long)N];                    \
      LBUF[j_] = (float)zn[(tb_ + j_ - 99) * (long)N];               \
    } }
#define PROC8(CBUF, LBUF, DOSTORE)                                   \
  { _Pragma("unroll")                                                \
    for (int j_ = 0; j_ < 8; ++j_) {                                 \
      double s = (u >= 1.0) ? 1.0 : 0.0;                             \
      if (DOSTORE) { sout[oa] = (Tout)s; oa += (size_t)strideT; }    \
      double xt = (double)CBUF[j_], x99 = (double)LBUF[j_];          \
      double pn = A1 * pp1 - A2 * pp2 + B1 * xt - C0 * x99           \
                  + C1 * xm100;                                      \
      xm100 = x99;                                                   \
      u = pn - 2.0 * ((e1 + e2) + s);                                \
      double t1 = e1 + s;                                            \
      e2 = AEXP * (e2 + t1); e1 = AEXP * t1;                         \
      pp2 = pp1; pp1 = pn;                                           \
    } }
  PREF8(cA, lA, ts)
  for (int g = 0; g < ngrp; g += 2) {
    PREF8(cB, lB, ts + (g + 1) * 8)
    PROC8(cA, lA, g >= nwg)
    PREF8(cA, lA, ts + (g + 2) * 8)    // last iter overshoots into slack
    PROC8(cB, lB, g + 1 >= nwg)
  }
#undef PREF8
#undef PROC8
}

// ---------------- conv2 as exact bf16-limb MFMA -----------------------------
__global__ __launch_bounds__(256, 2) void k_conv2_mfma(
    const unsigned char* __restrict__ s2b, const unsigned short* __restrict__ BL2g,
    float* __restrict__ z3) {
  __shared__ __align__(16) unsigned short bl2[15360];  // 30,720 B
  __shared__ unsigned char ls[4][1216];                // 4,864 B
  __shared__ int tab[160];                             // 640 B
  int tid = threadIdx.x;
  for (int i = tid; i < 7680; i += 256)
    ((unsigned int*)bl2)[i] = ((const unsigned int*)BL2g)[i];
  if (tid < 160) {
    int k = tid;
    int ci = k / 25, rem = k - ci * 25;
    int ky = rem / 5, kx = rem - ky * 5;
    tab[k] = (k < 150) ? (ci * 196 + ky * 14 + kx) : 0;
  }
  int w = tid >> 6, lane = tid & 63;
  int t = blockIdx.x * 4 + w;
  {
    const unsigned int* srow = (const unsigned int*)(s2b + (size_t)t * 1176);
    unsigned int* dst = (unsigned int*)ls[w];
    for (int i = lane; i < 294; i += 64) dst[i] = srow[i];
  }
  __syncthreads();
  int r = lane & 15, g = lane >> 4;
#pragma unroll
  for (int mt = 0; mt < 7; ++mt) {
    int p = mt * 16 + r;
    int pi = p / 10;
    int pioff = pi * 14 + (p - pi * 10);
    s16x8 a[5];
#pragma unroll
    for (int ks = 0; ks < 5; ++ks) {
      u16x8 f;
#pragma unroll
      for (int jj = 0; jj < 8; ++jj) {
        int k = ks * 32 + g * 8 + jj;
        bool v = (mt < 6 || p < 100) && (ks < 4 || k < 150);
        int idx = v ? (tab[k] + pioff) : 0;
        unsigned char byte = ls[w][idx];
        f[jj] = (v && byte) ? (unsigned short)0x3F80 : (unsigned short)0;
      }
      a[ks] = (s16x8)f;
    }
    double zacc[4] = {0.0, 0.0, 0.0, 0.0};
    double scale = 1.0;
    for (int j = 0; j < 6; ++j) {
      f32x4 C = (f32x4){0.f, 0.f, 0.f, 0.f};
#pragma unroll
      for (int ks = 0; ks < 5; ++ks) {
        const u16x8* bf = (const u16x8*)bl2 + (((j * 5 + ks) * 4 + g) * 16 + r);
        C = __builtin_amdgcn_mfma_f32_16x16x32_bf16(a[ks], (s16x8)(*bf), C, 0, 0, 0);
      }
#pragma unroll
      for (int q = 0; q < 4; ++q) zacc[q] += scale * (double)C[q];
      scale *= 256.0;
    }
#pragma unroll
    for (int q = 0; q < 4; ++q) {
      int pr = mt * 16 + g * 4 + q;
      if (pr < 100)
        z3[(size_t)t * 1600 + r * 100 + pr] = (float)(zacc[q] * (1.0 / FIXS));
    }
  }
}

// ---------------- dense1 bf16-limb MFMA: kc-split, 2 blocks/CU --------------
// 512 blocks x 512 thr: xcd=bid&7 -> ct=xcd&3, kc=xcd>>2 (each XCD L2 holds
// one 860KB quarter-panel); bm=bid>>3 in 0..63 (32-row tile). Wave w: subtile
// sub=w>>2 (16 rows), k-chunk kch=w&3, ks0=kc*28+kch*7 over zero-padded
// KSP=56. 4-way f32 reduce per limb (exact ints < 2^17) via 43KB LDS; 10
// reduce targets (2 sub x 5 nt): primary tt=w, secondary tt=8+w for w<2.
// Halves write disjoint f64 zpart (exact; one writer per element).
__global__ __launch_bounds__(512, 4) void k_mfma_dense1(
    const unsigned char* __restrict__ s3b, const unsigned short* __restrict__ BL,
    double* __restrict__ zpart) {
  __shared__ float redf[8][64][21];     // 43,008 B
  int bid = blockIdx.x;
  int xcd = bid & 7;
  int ct = xcd & 3;
  int kc = xcd >> 2;
  int bm = bid >> 3;                    // 0..63
  int col0 = ct * 80;
  int w = threadIdx.x >> 6, lane = threadIdx.x & 63;
  int r = lane & 15, g = lane >> 4;
  int sub = w >> 2, kch = w & 3;
  int ks0 = kc * 28 + kch * 7;
  int row = bm * 32 + sub * 16 + r;
  const unsigned char* ab = s3b + (size_t)row * 1600 + ks0 * 32 + g * 8;

  // hoist 7 A fragments (static unroll, rule #20). ks up to 55: overshoot
  // reads land in s4b (in-bounds ws), multiplied by zero B limbs.
  s16x8 a[7];
#pragma unroll
  for (int ks = 0; ks < 7; ++ks) {
    unsigned long long bits = *(const unsigned long long*)(ab + ks * 32);
    u16x8 f;
#pragma unroll
    for (int jj = 0; jj < 8; ++jj)
      f[jj] = ((bits >> (8 * jj)) & 1ULL) ? (unsigned short)0x3F80
                                          : (unsigned short)0;
    a[ks] = (s16x8)f;
  }

  double zawP[4] = {0.0, 0.0, 0.0, 0.0};
  double zawS[4] = {0.0, 0.0, 0.0, 0.0};  // waves 0,1 only
  double scale = 1.0;
  for (int j = 0; j < 6; ++j) {
    f32x4 C[5];
#pragma unroll
    for (int nt = 0; nt < 5; ++nt) C[nt] = (f32x4){0.f, 0.f, 0.f, 0.f};
#pragma unroll
    for (int ks = 0; ks < 7; ++ks) {   // branch-free, fully static
      const u16x8* bb =
          (const u16x8*)BL + ((size_t)((j * KSP + ks0 + ks) * 320 + col0 + r)) * 4 + g;
#pragma unroll
      for (int nt = 0; nt < 5; ++nt)
        C[nt] = __builtin_amdgcn_mfma_f32_16x16x32_bf16(
            a[ks], (s16x8)bb[nt * 64], C[nt], 0, 0, 0);
    }
#pragma unroll
    for (int nt = 0; nt < 5; ++nt)
#pragma unroll
      for (int q = 0; q < 4; ++q)
        redf[w][lane][nt * 4 + q] = C[nt][q];
    __syncthreads();
    {   // primary target tt = w: sub = tt/5, nt = tt%5 (wave-uniform)
      int s = w / 5, nt = w - s * 5;
      int base = s * 4;
#pragma unroll
      for (int q = 0; q < 4; ++q) {
        int i = nt * 4 + q;
        float sm = (redf[base + 0][lane][i] + redf[base + 1][lane][i]) +
                   (redf[base + 2][lane][i] + redf[base + 3][lane][i]);
        zawP[q] += scale * (double)sm;
      }
    }
    if (w < 2) {  // secondary target tt = 8+w: sub=1, nt=3+w
      int nt = 3 + w;
#pragma unroll
      for (int q = 0; q < 4; ++q) {
        int i = nt * 4 + q;
        float sm = (redf[4][lane][i] + redf[5][lane][i]) +
                   (redf[6][lane][i] + redf[7][lane][i]);
        zawS[q] += scale * (double)sm;
      }
    }
    __syncthreads();
    scale *= 256.0;
  }

  double* zp = zpart + (size_t)kc * (2048 * 320);
  {
    int s = w / 5, nt = w - s * 5;
    int rowo = bm * 32 + s * 16 + g * 4;
    int col = col0 + nt * 16 + r;
#pragma unroll
    for (int q = 0; q < 4; ++q)
      zp[(size_t)(rowo + q) * 320 + col] = zawP[q];
  }
  if (w < 2) {
    int nt = 3 + w;
    int rowo = bm * 32 + 16 + g * 4;
    int col = col0 + nt * 16 + r;
#pragma unroll
    for (int q = 0; q < 4; ++q)
      zp[(size_t)(rowo + q) * 320 + col] = zawS[q];
  }
}

// ---------------- dense1 combine: z4 = (zpart0 + zpart1) * 2^-45 ------------
__global__ __launch_bounds__(256) void k_combine1(const double* __restrict__ zpart,
                                                  float* __restrict__ z4) {
  int idx = blockIdx.x * 256 + threadIdx.x;
  if (idx >= 2048 * 300) return;
  int t = idx / 300, o = idx - t * 300;
  size_t b = (size_t)t * 320 + o;
  z4[idx] = (float)((zpart[b] + zpart[b + 655360]) * (1.0 / FIXS));
}

// ---------------- sparse dense: one output per lane -------------------------
template <int NIN, int NOUT, int BLK>
__global__ __launch_bounds__(BLK) void k_dense_sparse(
    const unsigned char* __restrict__ s, const float* __restrict__ WT,
    float* __restrict__ z) {
  constexpr int NCH = (NIN + BLK - 1) / BLK;
  constexpr int NW = BLK / 64;
  __shared__ __align__(16) int list[NIN];
  __shared__ int wcnt[NCH][NW];
  int t = blockIdx.x;
  const unsigned char* srow = s + (size_t)t * NIN;
  int tid = threadIdx.x, lane = tid & 63, wv = tid >> 6;
  unsigned long long msave[NCH];
  bool asave[NCH];
#pragma unroll
  for (int ci = 0; ci < NCH; ++ci) {
    int c = ci * BLK + tid;
    bool a = (c < NIN) && (srow[c] != 0);
    unsigned long long m = __ballot(a);
    msave[ci] = m; asave[ci] = a;
    if (lane == 0) wcnt[ci][wv] = __popcll(m);
  }
  __syncthreads();
  int nact = 0;
#pragma unroll
  for (int ci = 0; ci < NCH; ++ci) {
    int off = nact;
    for (int w = 0; w < wv; ++w) off += wcnt[ci][w];
    if (asave[ci])
      list[off + __popcll(msave[ci] & ((1ULL << lane) - 1))] = ci * BLK + tid;
    for (int w = 0; w < NW; ++w) nact += wcnt[ci][w];
  }
  __syncthreads();
  if (tid >= NOUT) return;
  const float* col = WT + tid;
  double a0 = 0.0, a1 = 0.0, a2 = 0.0, a3 = 0.0;
  int k = 0, nact4 = nact & ~3;
  for (; k < nact4; k += 4) {
    int4 l4 = *(const int4*)&list[k];
    a0 += (double)col[(size_t)l4.x * NOUT];
    a1 += (double)col[(size_t)l4.y * NOUT];
    a2 += (double)col[(size_t)l4.z * NOUT];
    a3 += (double)col[(size_t)l4.w * NOUT];
  }
  for (; k < nact; ++k) a0 += (double)col[(size_t)list[k] * NOUT];
  z[(size_t)t * NOUT + tid] = (float)((a0 + a1) + (a2 + a3));
}

// ---------------- launch ----------------------------------------------------
extern "C" void kernel_launch(void* const* d_in, const int* in_sizes, int n_in,
                              void* d_out, int out_size, void* d_ws, size_t ws_size,
                              hipStream_t stream) {
  const float* x   = (const float*)d_in[0];
  const float* Wc1 = (const float*)d_in[1];
  const float* Wc2 = (const float*)d_in[2];
  const float* Wf1 = (const float*)d_in[3];
  const float* Wf2 = (const float*)d_in[4];
  const float* Wf3 = (const float*)d_in[5];
  float* out = (float*)d_out;
  char* ws = (char*)d_ws;

  // Workspace (~40 MB). Zeroed pads below zA / y2b serve FIR/IIR negative-
  // row reads. zpart (10.5 MB, f64) overlays PADY+y2b+s1b -- all dead when
  // dense1 runs, and rewritten every replay (memset/scan1/pool) beforehand.
  double* Scum = (double*)(ws + 0);                   // double[100]
  double* Htab = (double*)(ws + 2048);                // double[102]
  float*  c1   = (float*)(ws + 4096);                 // float[4704]
  const size_t PADZ = 65536;                          // 655360 B zeros
  const size_t ZA   = PADZ + 655360;                  // 720896
  const size_t PADY = ZA + 13107200 + 262144;         // 14090240 (131072 zeros)
  const size_t Y2B  = PADY + 131072;                  // 14221312
  const size_t S1B  = Y2B + 2408448 + 65536;          // 16695296
  const size_t S2B  = S1B + 9633792;                  // 26329088
  const size_t S3B  = S2B + 2408448;                  // 28737536
  const size_t S4B  = S3B + 3276800;                  // 32014336
  const size_t S5B  = S4B + 614400;                   // 32628736
  const size_t WB   = S5B + 307200;                   // 32935936 WT2
  const size_t WC   = WB + 180000;                    // 33115936 WT3
  const size_t BLa  = 33122000;                       // BL: 6,881,280 (16-al.)
  const size_t BL2a = BLa + 6881280;                  // 40003280 (16-aligned)
  float* zA = (float*)(ws + ZA);
  unsigned char* y2b = (unsigned char*)(ws + Y2B);
  unsigned char* s1b = (unsigned char*)(ws + S1B);
  unsigned char* s2b = (unsigned char*)(ws + S2B);
  unsigned char* s3b = (unsigned char*)(ws + S3B);
  unsigned char* s4b = (unsigned char*)(ws + S4B);
  unsigned char* s5b = (unsigned char*)(ws + S5B);
  float* WT2 = (float*)(ws + WB);
  float* WT3 = (float*)(ws + WC);
  unsigned short* BLp  = (unsigned short*)(ws + BLa);
  unsigned short* BL2p = (unsigned short*)(ws + BL2a);  // 30,720 B
  double* zpart = (double*)(ws + PADY);               // 10,485,760 B overlay

  // IIR coefficients (host, double): h[k] = c*k*b^k, truncated at K=100.
  double b = exp(-0.1), c = 0.1 * exp(1.0);
  double A1 = 2.0 * b, A2 = b * b;
  double B1 = c * b;
  double C0 = 100.0 * c * pow(b, 100.0);
  double C1 = 99.0 * c * pow(b, 101.0);
  double sc = (double)1.1f;                  // pool weight, exact fp32 value

  hipMemsetAsync(ws + PADZ, 0, 655360, stream);
  hipMemsetAsync(ws + PADY, 0, 131072, stream);
  k_prep<<<484, 256, 0, stream>>>(x, Wc1, Wc2, Wf1, Wf2, Wf3, c1, Scum, Htab,
                                  WT2, WT3, BLp, BL2p);
  k_scan1_chunk<<<NCHK * 4704 / 256, 256, 0, stream>>>(c1, Scum, s1b);
  k_pool<<<(1176 * T_BINS) / 256, 256, 0, stream>>>(s1b, y2b);
  k_psp_scan_chunk<unsigned char, unsigned char>
      <<<(NCHK * 1176 + 255) / 256, 256, 0, stream>>>(
      y2b, s2b, 1176, 1176L, 1L, Htab, A1, A2, B1 * sc, C0 * sc, C1 * sc, sc);
  k_conv2_mfma<<<T_BINS / 4, 256, 0, stream>>>(s2b, BL2p, zA);
  k_psp_scan_chunk<float, unsigned char>
      <<<(NCHK * 1600 + 255) / 256, 256, 0, stream>>>(
      zA, s3b, 1600, 1600L, 1L, Htab, A1, A2, B1, C0, C1, 1.0);
  k_mfma_dense1<<<512, 512, 0, stream>>>(s3b, BLp, zpart);
  k_combine1<<<(2048 * 300 + 255) / 256, 256, 0, stream>>>(zpart, zA);
  k_psp_scan_chunk<float, unsigned char>
      <<<(NCHK * 300 + 255) / 256, 256, 0, stream>>>(
      zA, s4b, 300, 300L, 1L, Htab, A1, A2, B1, C0, C1, 1.0);
  k_dense_sparse<300, 150, 192><<<T_BINS, 192, 0, stream>>>(s4b, WT2, zA);
  k_psp_scan_chunk<float, unsigned char>
      <<<(NCHK * 150 + 255) / 256, 256, 0, stream>>>(
      zA, s5b, 150, 150L, 1L, Htab, A1, A2, B1, C0, C1, 1.0);
  k_dense_sparse<150, 10, 64><<<T_BINS, 64, 0, stream>>>(s5b, WT3, zA);
  k_psp_scan_chunk<float, float>
      <<<(NCHK * 10 + 255) / 256, 256, 0, stream>>>(
      zA, out, 10, 1L, 2048L, Htab, A1, A2, B1, C0, C1, 1.0);

  (void)in_sizes; (void)n_in; (void)out_size; (void)ws_size;
}

// Round 23
// 198.841 us; speedup vs baseline: 1.0675x; 1.0675x over previous
//
#include <hip/hip_runtime.h>
#include <math.h>

// SLAYER SNN forward, 6 layers, T=2048.  (R23 = exact revert to the R21
// best-measured configuration: 198.8 us, absmax 0. R22's kc-split regressed
// -- zpart round-trip traffic > occupancy gain.)
//
// Policy: compute near the TRUE value (error << reference's own fp32 noise
// ~1e-5) so binary spike decisions match the golden fp32 reference exactly.
//
// PSP = exact 2nd-order IIR of the truncated SRM kernel; refractory = 2-state
// recurrence; time-chunked speculative scan (64 chunks x 32 steps, 48-step
// warmup -- WUP=48 proven R7; chunks with t0<WUP start at ts=0 EXACTLY).
//
// DENSE1 (1600->300) and CONV2 as EXACT fixed-point bf16 MFMA:
//   w_fixed = round(w*2^45) = sum_{j<6} d_j 256^j, d_j signed 8-bit digits.
//   Digits and 0/1 spikes are exact in bf16; mfma_f32_16x16x32_bf16
//   accumulates integer partial sums -> EXACT in f32 C (< 2^24). Cross-wave
//   reduce (dense1) in F32 (8-way sums of exact ints -> exact), f64 limb
//   combine (terms integer x 2^(8j); residual ~1e-12 weight units).

#define T_BINS 2048
#define K_SRM  100
#define AEXP   0.36787944117144233   // e^-1
#define CHK    32                    // chunk output length
#define WUP    48                    // refractory warmup length (proven R7)
#define NCHK   (T_BINS / CHK)        // 64
#define FIXS   35184372088832.0      // 2^45
#define KSP    56                    // dense1 padded ks count (50 real + 6)

typedef __attribute__((ext_vector_type(8))) short          s16x8;
typedef __attribute__((ext_vector_type(8))) unsigned short u16x8;
typedef __attribute__((ext_vector_type(4))) float          f32x4;

// ---------------- fused prep: conv1 + packB + packB2 + transposes + init ----
__global__ __launch_bounds__(256) void k_prep(
    const float* __restrict__ x, const float* __restrict__ Wc1,
    const float* __restrict__ Wc2, const float* __restrict__ Wf1,
    const float* __restrict__ Wf2, const float* __restrict__ Wf3,
    float* __restrict__ c1, double* __restrict__ Scum, double* __restrict__ H,
    float* __restrict__ WT2, float* __restrict__ WT3,
    unsigned short* __restrict__ BL, unsigned short* __restrict__ BL2) {
  int b = blockIdx.x, tid = threadIdx.x;
  if (b < 19) {                         // ---- conv1 -> c1[4704]
    int idx = b * 256 + tid;
    if (idx >= 4704) return;
    int o = idx / 784, r = idx % 784, i = r / 28, j = r % 28;
    double acc = 0.0;
    for (int ci = 0; ci < 3; ++ci)
      for (int ky = 0; ky < 5; ++ky) {
        const float* xr = x + ci * 1024 + (i + ky) * 32 + j;
        const float* wr = Wc1 + ((o * 3 + ci) * 5 + ky) * 5;
#pragma unroll
        for (int kx = 0; kx < 5; ++kx)
          acc += (double)xr[kx] * (double)wr[kx];
      }
    c1[idx] = (float)acc;
  } else if (b < 299) {                 // ---- packB (dense1): 6 bf16 limbs
    int idx = (b - 19) * 256 + tid;     // 56 ks x 320 n x 4 g = 71680
    if (idx >= KSP * 320 * 4) return;
    int g = idx & 3, rest = idx >> 2;
    int n = rest % 320, ks = rest / 320;
    u16x8 out[6];
#pragma unroll
    for (int j = 0; j < 6; ++j)
#pragma unroll
      for (int jj = 0; jj < 8; ++jj) out[j][jj] = 0;
    if (n < 300 && ks < 50) {
      const float* wr = Wf1 + (size_t)n * 1600 + ks * 32 + g * 8;
#pragma unroll
      for (int jj = 0; jj < 8; ++jj) {
        long long v = llrint((double)wr[jj] * FIXS);
#pragma unroll
        for (int j = 0; j < 6; ++j) {
          int d = (int)(signed char)(v & 0xFF);
          v = (v - d) >> 8;
          float fd = (float)d;               // exact; bf16 truncation exact
          unsigned int fb = __float_as_uint(fd);
          out[j][jj] = (unsigned short)(fb >> 16);
        }
      }
    }
#pragma unroll
    for (int j = 0; j < 6; ++j)
      ((u16x8*)BL)[((j * KSP + ks) * 320 + n) * 4 + g] = out[j];
  } else if (b < 481) {                 // ---- WT2 / WT3 transposes
    int idx = (b - 299) * 256 + tid;
    if (idx < 45000) {
      int c = idx / 150, o = idx - c * 150;
      WT2[idx] = Wf2[o * 300 + c];
    } else if (idx < 46500) {
      int j = idx - 45000, c = j / 10, o = j - c * 10;
      WT3[j] = Wf3[o * 150 + c];
    }
  } else if (b < 483) {                 // ---- packB2 (conv2): 6 bf16 limbs
    int idx = (b - 481) * 256 + tid;    // 5 ks x 16 o x 4 g = 320
    if (idx >= 320) return;
    int g = idx & 3, rest = idx >> 2;
    int o = rest & 15, ks = rest >> 4;  // ks in 0..4
    u16x8 out[6];
#pragma unroll
    for (int j = 0; j < 6; ++j)
#pragma unroll
      for (int jj = 0; jj < 8; ++jj) out[j][jj] = 0;
#pragma unroll
    for (int jj = 0; jj < 8; ++jj) {
      int k = ks * 32 + g * 8 + jj;
      if (k < 150) {
        long long v = llrint((double)Wc2[o * 150 + k] * FIXS);
#pragma unroll
        for (int j = 0; j < 6; ++j) {
          int d = (int)(signed char)(v & 0xFF);
          v = (v - d) >> 8;
          float fd = (float)d;
          unsigned int fb = __float_as_uint(fd);
          out[j][jj] = (unsigned short)(fb >> 16);
        }
      }
    }
#pragma unroll
    for (int j = 0; j < 6; ++j)          // lane-contiguous layout: r fastest
      ((u16x8*)BL2)[((j * 5 + ks) * 4 + g) * 16 + o] = out[j];
  } else {                              // ---- init tables
    if (tid == 0) {
      double acc = 0.0;
      for (int k = 0; k < K_SRM; ++k) {
        double tk = (double)k;
        double h = (tk * 0.1) * exp(1.0 - tk * 0.1);
        H[k] = h; acc += h; Scum[k] = acc;
      }
      H[100] = 0.0; H[101] = 0.0;
    }
  }
}

// ---------------- layer1 chunked scan: p1[t] = c1*Scum[t] -------------------
__global__ __launch_bounds__(256) void k_scan1_chunk(
    const float* __restrict__ c1, const double* __restrict__ Scum_g,
    unsigned char* __restrict__ s1b) {
  __shared__ double Sc[K_SRM];
  for (int k = threadIdx.x; k < K_SRM; k += 256) Sc[k] = Scum_g[k];
  __syncthreads();
  int idx = blockIdx.x * 256 + threadIdx.x;
  int chunk = idx / 4704, n = idx - chunk * 4704;
  int t0 = chunk * CHK;
  int ts = t0 - WUP; if (ts < 0) ts = 0;   // ts==0 -> exact init
  double w = (double)c1[n];
  double e1 = 0.0, e2 = 0.0;
  double u = w * Sc[ts < (K_SRM - 1) ? ts : (K_SRM - 1)];
  unsigned char* outp = s1b + n;
  for (int t = ts; t < t0; ++t) {       // warmup, no store
    double s = (u >= 1.0) ? 1.0 : 0.0;
    int si = t + 1 < (K_SRM - 1) ? t + 1 : (K_SRM - 1);
    u = w * Sc[si] - 2.0 * ((e1 + e2) + s);
    double t1 = e1 + s;
    e2 = AEXP * (e2 + t1); e1 = AEXP * t1;
  }
#pragma unroll 8
  for (int t = t0; t < t0 + CHK; ++t) { // output
    double s = (u >= 1.0) ? 1.0 : 0.0;
    outp[(size_t)t * 4704] = (unsigned char)s;
    int si = t + 1 < (K_SRM - 1) ? t + 1 : (K_SRM - 1);
    u = w * Sc[si] - 2.0 * ((e1 + e2) + s);
    double t1 = e1 + s;
    e2 = AEXP * (e2 + t1); e1 = AEXP * t1;
  }
}

// ---------------- pool: 2x2 spike count -> y2b[t][1176] bytes ---------------
__global__ __launch_bounds__(256) void k_pool(const unsigned char* __restrict__ s1b,
                                              unsigned char* __restrict__ y2b) {
  int idx = blockIdx.x * blockDim.x + threadIdx.x;
  if (idx >= 1176 * T_BINS) return;
  int t = idx / 1176, n2 = idx - t * 1176;
  int c = n2 / 196, r = n2 % 196, i = r / 14, j = r % 14;
  const unsigned char* b = s1b + (size_t)t * 4704 + c * 784 + (2 * i) * 28 + 2 * j;
  y2b[idx] = (unsigned char)((int)b[0] + (int)b[1] + (int)b[28] + (int)b[29]);
}

// ---------------- chunked fused PSP(IIR) + spike scan -----------------------
template <typename Tin, typename Tout>
__global__ __launch_bounds__(256) void k_psp_scan_chunk(
    const Tin* __restrict__ z, Tout* __restrict__ sout, int N,
    long strideT, long strideN, const double* __restrict__ H_g,
    double A1, double A2, double B1, double C0, double C1, double xscale) {
  __shared__ double Hs[102];
  for (int k = threadIdx.x; k < 102; k += 256) Hs[k] = H_g[k];
  __syncthreads();
  int idx = blockIdx.x * blockDim.x + threadIdx.x;
  if (idx >= NCHK * N) return;
  int chunk = idx / N, n = idx - chunk * N;
  int t0 = chunk * CHK;
  int ts = t0 - WUP; if (ts < 0) ts = 0;   // ts==0 -> exact init
  const Tin* zn = z + n;

  // exact IIR init: accA=p[ts], accB=p[ts-1] (100-tap FIR, 10-deep pipe)
  double accA = 0.0, accB = 0.0;
  float fA[10], fB[10];
#define LOADF(BUF, J0)                                               \
  { _Pragma("unroll")                                                \
    for (int q_ = 0; q_ < 10; ++q_)                                  \
      BUF[q_] = (float)zn[(long)(ts - 1 - ((J0) + q_)) * (long)N]; }
#define FMA10(BUF, J0)                                               \
  { _Pragma("unroll")                                                \
    for (int q_ = 0; q_ < 10; ++q_) {                                \
      double v_ = (double)BUF[q_];                                   \
      accA += Hs[(J0) + q_ + 1] * v_;                                \
      accB += Hs[(J0) + q_] * v_;                                    \
    } }
  LOADF(fA, 0)
  for (int q = 0; q < 100; q += 20) {
    LOADF(fB, q + 10)
    FMA10(fA, q)
    LOADF(fA, q + 20)                  // q=80: overshoot, in-bounds, unused
    FMA10(fB, q + 10)
  }
#undef LOADF
#undef FMA10
  double pp1 = accA * xscale;          // p[ts]
  double pp2 = accB * xscale;          // p[ts-1]
  double xm100 = (double)(float)zn[(long)(ts - 100) * (long)N];
  double u = pp1, e1 = 0.0, e2 = 0.0;  // refractory zero (exact at ts==0)

  float cA[8], cB[8], lA[8], lB[8];
  size_t oa = (size_t)n * (size_t)strideN + (size_t)t0 * (size_t)strideT;
  int nwg = (t0 - ts) >> 3;            // 0, 4, or 6 warmup groups
  int ngrp = nwg + CHK / 8;            // 4, 8, or 10 (even)
#define PREF8(CBUF, LBUF, TB)                                        \
  { long tb_ = (long)(TB);                                           \
    _Pragma("unroll")                                                \
    for (int j_ = 0; j_ < 8; ++j_) {                                 \
      CBUF[j_] = (float)zn[(tb_ + j_) * (long)N];                    \
      LBUF[j_] = (float)zn[(tb_ + j_ - 99) * (long)N];               \
    } }
#define PROC8(CBUF, LBUF, DOSTORE)                                   \
  { _Pragma("unroll")                                                \
    for (int j_ = 0; j_ < 8; ++j_) {                                 \
      double s = (u >= 1.0) ? 1.0 : 0.0;                             \
      if (DOSTORE) { sout[oa] = (Tout)s; oa += (size_t)strideT; }    \
      double xt = (double)CBUF[j_], x99 = (double)LBUF[j_];          \
      double pn = A1 * pp1 - A2 * pp2 + B1 * xt - C0 * x99           \
                  + C1 * xm100;                                      \
      xm100 = x99;                                                   \
      u = pn - 2.0 * ((e1 + e2) + s);                                \
      double t1 = e1 + s;                                            \
      e2 = AEXP * (e2 + t1); e1 = AEXP * t1;                         \
      pp2 = pp1; pp1 = pn;                                           \
    } }
  PREF8(cA, lA, ts)
  for (int g = 0; g < ngrp; g += 2) {
    PREF8(cB, lB, ts + (g + 1) * 8)
    PROC8(cA, lA, g >= nwg)
    PREF8(cA, lA, ts + (g + 2) * 8)    // last iter overshoots into slack
    PROC8(cB, lB, g + 1 >= nwg)
  }
#undef PREF8
#undef PROC8
}

// ---------------- conv2 as exact bf16-limb MFMA -----------------------------
// 512 blocks x 256 thr (4 waves = 4 t). Per t: C[p][o], 7 m-tiles of 16,
// K=150 zero-padded to 160 (5 ks of 32), N=16 (one tile). B limbs (30KB) +
// spike rows + im2col offset table staged in LDS. A-fragments built from
// LDS bytes (predicated, static idx). Per-limb C exact (<150*128 < 2^24);
// f64 limb combine. D: col=lane&15 (o), row=(lane>>4)*4+q (p).
__global__ __launch_bounds__(256, 2) void k_conv2_mfma(
    const unsigned char* __restrict__ s2b, const unsigned short* __restrict__ BL2g,
    float* __restrict__ z3) {
  __shared__ __align__(16) unsigned short bl2[15360];  // 30,720 B
  __shared__ unsigned char ls[4][1216];                // 4,864 B
  __shared__ int tab[160];                             // 640 B
  int tid = threadIdx.x;
  for (int i = tid; i < 7680; i += 256)
    ((unsigned int*)bl2)[i] = ((const unsigned int*)BL2g)[i];
  if (tid < 160) {
    int k = tid;
    int ci = k / 25, rem = k - ci * 25;
    int ky = rem / 5, kx = rem - ky * 5;
    tab[k] = (k < 150) ? (ci * 196 + ky * 14 + kx) : 0;
  }
  int w = tid >> 6, lane = tid & 63;
  int t = blockIdx.x * 4 + w;
  {
    const unsigned int* srow = (const unsigned int*)(s2b + (size_t)t * 1176);
    unsigned int* dst = (unsigned int*)ls[w];
    for (int i = lane; i < 294; i += 64) dst[i] = srow[i];
  }
  __syncthreads();
  int r = lane & 15, g = lane >> 4;
#pragma unroll
  for (int mt = 0; mt < 7; ++mt) {
    int p = mt * 16 + r;
    int pi = p / 10;
    int pioff = pi * 14 + (p - pi * 10);
    s16x8 a[5];
#pragma unroll
    for (int ks = 0; ks < 5; ++ks) {
      u16x8 f;
#pragma unroll
      for (int jj = 0; jj < 8; ++jj) {
        int k = ks * 32 + g * 8 + jj;
        bool v = (mt < 6 || p < 100) && (ks < 4 || k < 150);
        int idx = v ? (tab[k] + pioff) : 0;
        unsigned char byte = ls[w][idx];
        f[jj] = (v && byte) ? (unsigned short)0x3F80 : (unsigned short)0;
      }
      a[ks] = (s16x8)f;
    }
    double zacc[4] = {0.0, 0.0, 0.0, 0.0};
    double scale = 1.0;
    for (int j = 0; j < 6; ++j) {
      f32x4 C = (f32x4){0.f, 0.f, 0.f, 0.f};
#pragma unroll
      for (int ks = 0; ks < 5; ++ks) {
        const u16x8* bf = (const u16x8*)bl2 + (((j * 5 + ks) * 4 + g) * 16 + r);
        C = __builtin_amdgcn_mfma_f32_16x16x32_bf16(a[ks], (s16x8)(*bf), C, 0, 0, 0);
      }
#pragma unroll
      for (int q = 0; q < 4; ++q) zacc[q] += scale * (double)C[q];
      scale *= 256.0;
    }
#pragma unroll
    for (int q = 0; q < 4; ++q) {
      int pr = mt * 16 + g * 4 + q;
      if (pr < 100)
        z3[(size_t)t * 1600 + r * 100 + pr] = (float)(zacc[q] * (1.0 / FIXS));
    }
  }
}

// ---------------- dense1 bf16-limb MFMA: M-blocked, single-phase reduce -----
// 256 blocks x 512 thr (8 waves): xcd=bid&7, ct=xcd&3 (one B-panel per XCD
// L2), bm=(bid>>3)|((xcd>>2)<<5) in 0..63 (32-row tile). Wave w owns ks
// [7w,7w+7) over zero-padded KSP=56; computes TWO 16-row subtiles with each
// B fragment. ONE reduce phase per limb via redf[8][64][41] (82KB LDS).
__global__ __launch_bounds__(512, 2) void k_mfma_dense1(
    const unsigned char* __restrict__ s3b, const unsigned short* __restrict__ BL,
    float* __restrict__ z4) {
  __shared__ float redf[8][64][41];     // 83,968 B
  int bid = blockIdx.x;
  int xcd = bid & 7;
  int ct = xcd & 3;
  int bm = (bid >> 3) | ((xcd >> 2) << 5);     // 0..63
  int col0 = ct * 80;
  int w = threadIdx.x >> 6, lane = threadIdx.x & 63;
  int r = lane & 15, g = lane >> 4;
  int ks0 = w * 7;
  int rowA = bm * 32 + r, rowB = rowA + 16;
  const unsigned char* abA = s3b + (size_t)rowA * 1600 + ks0 * 32 + g * 8;
  const unsigned char* abB = s3b + (size_t)rowB * 1600 + ks0 * 32 + g * 8;

  // hoist A fragments for both subtiles (static unroll, rule #20)
  s16x8 aA[7], aB[7];
#pragma unroll
  for (int ks = 0; ks < 7; ++ks) {
    unsigned long long bA = *(const unsigned long long*)(abA + ks * 32);
    unsigned long long bB = *(const unsigned long long*)(abB + ks * 32);
    u16x8 fa, fb;
#pragma unroll
    for (int jj = 0; jj < 8; ++jj) {
      fa[jj] = ((bA >> (8 * jj)) & 1ULL) ? (unsigned short)0x3F80
                                         : (unsigned short)0;
      fb[jj] = ((bB >> (8 * jj)) & 1ULL) ? (unsigned short)0x3F80
                                         : (unsigned short)0;
    }
    aA[ks] = (s16x8)fa; aB[ks] = (s16x8)fb;
  }

  double zawA[4] = {0.0, 0.0, 0.0, 0.0};  // waves w<5 accumulate (nt = w)
  double zawB[4] = {0.0, 0.0, 0.0, 0.0};
  double scale = 1.0;
  for (int j = 0; j < 6; ++j) {
    f32x4 CA[5], CB[5];
#pragma unroll
    for (int nt = 0; nt < 5; ++nt) {
      CA[nt] = (f32x4){0.f, 0.f, 0.f, 0.f};
      CB[nt] = (f32x4){0.f, 0.f, 0.f, 0.f};
    }
#pragma unroll
    for (int ks = 0; ks < 7; ++ks) {   // branch-free, fully static
      const u16x8* bb =
          (const u16x8*)BL + ((size_t)((j * KSP + ks0 + ks) * 320 + col0 + r)) * 4 + g;
#pragma unroll
      for (int nt = 0; nt < 5; ++nt) {
        s16x8 bf = (s16x8)bb[nt * 64];
        CA[nt] = __builtin_amdgcn_mfma_f32_16x16x32_bf16(aA[ks], bf, CA[nt], 0, 0, 0);
        CB[nt] = __builtin_amdgcn_mfma_f32_16x16x32_bf16(aB[ks], bf, CB[nt], 0, 0, 0);
      }
    }
    // ---- single-phase reduce: CA -> 0..19, CB -> 20..39
#pragma unroll
    for (int nt = 0; nt < 5; ++nt)
#pragma unroll
      for (int q = 0; q < 4; ++q) {
        redf[w][lane][nt * 4 + q]      = CA[nt][q];
        redf[w][lane][20 + nt * 4 + q] = CB[nt][q];
      }
    __syncthreads();
    if (w < 5) {
#pragma unroll
      for (int q = 0; q < 4; ++q) {
        int i = w * 4 + q;
        float sA = ((redf[0][lane][i] + redf[1][lane][i]) +
                    (redf[2][lane][i] + redf[3][lane][i])) +
                   ((redf[4][lane][i] + redf[5][lane][i]) +
                    (redf[6][lane][i] + redf[7][lane][i]));
        int i2 = 20 + i;
        float sB = ((redf[0][lane][i2] + redf[1][lane][i2]) +
                    (redf[2][lane][i2] + redf[3][lane][i2])) +
                   ((redf[4][lane][i2] + redf[5][lane][i2]) +
                    (redf[6][lane][i2] + redf[7][lane][i2]));
        zawA[q] += scale * (double)sA;
        zawB[q] += scale * (double)sB;
      }
    }
    __syncthreads();
    scale *= 256.0;
  }

  if (w < 5) {
    int col = col0 + w * 16 + r;       // nt = w
    if (col < 300) {
      int rA0 = bm * 32 + g * 4, rB0 = rA0 + 16;
#pragma unroll
      for (int q = 0; q < 4; ++q) {
        z4[(size_t)(rA0 + q) * 300 + col] = (float)(zawA[q] * (1.0 / FIXS));
        z4[(size_t)(rB0 + q) * 300 + col] = (float)(zawB[q] * (1.0 / FIXS));
      }
    }
  }
}

// ---------------- sparse dense: one output per lane -------------------------
template <int NIN, int NOUT, int BLK>
__global__ __launch_bounds__(BLK) void k_dense_sparse(
    const unsigned char* __restrict__ s, const float* __restrict__ WT,
    float* __restrict__ z) {
  constexpr int NCH = (NIN + BLK - 1) / BLK;
  constexpr int NW = BLK / 64;
  __shared__ __align__(16) int list[NIN];
  __shared__ int wcnt[NCH][NW];
  int t = blockIdx.x;
  const unsigned char* srow = s + (size_t)t * NIN;
  int tid = threadIdx.x, lane = tid & 63, wv = tid >> 6;
  unsigned long long msave[NCH];
  bool asave[NCH];
#pragma unroll
  for (int ci = 0; ci < NCH; ++ci) {
    int c = ci * BLK + tid;
    bool a = (c < NIN) && (srow[c] != 0);
    unsigned long long m = __ballot(a);
    msave[ci] = m; asave[ci] = a;
    if (lane == 0) wcnt[ci][wv] = __popcll(m);
  }
  __syncthreads();
  int nact = 0;
#pragma unroll
  for (int ci = 0; ci < NCH; ++ci) {
    int off = nact;
    for (int w = 0; w < wv; ++w) off += wcnt[ci][w];
    if (asave[ci])
      list[off + __popcll(msave[ci] & ((1ULL << lane) - 1))] = ci * BLK + tid;
    for (int w = 0; w < NW; ++w) nact += wcnt[ci][w];
  }
  __syncthreads();
  if (tid >= NOUT) return;
  const float* col = WT + tid;
  double a0 = 0.0, a1 = 0.0, a2 = 0.0, a3 = 0.0;
  int k = 0, nact4 = nact & ~3;
  for (; k < nact4; k += 4) {
    int4 l4 = *(const int4*)&list[k];
    a0 += (double)col[(size_t)l4.x * NOUT];
    a1 += (double)col[(size_t)l4.y * NOUT];
    a2 += (double)col[(size_t)l4.z * NOUT];
    a3 += (double)col[(size_t)l4.w * NOUT];
  }
  for (; k < nact; ++k) a0 += (double)col[(size_t)list[k] * NOUT];
  z[(size_t)t * NOUT + tid] = (float)((a0 + a1) + (a2 + a3));
}

// ---------------- launch ----------------------------------------------------
extern "C" void kernel_launch(void* const* d_in, const int* in_sizes, int n_in,
                              void* d_out, int out_size, void* d_ws, size_t ws_size,
                              hipStream_t stream) {
  const float* x   = (const float*)d_in[0];
  const float* Wc1 = (const float*)d_in[1];
  const float* Wc2 = (const float*)d_in[2];
  const float* Wf1 = (const float*)d_in[3];
  const float* Wf2 = (const float*)d_in[4];
  const float* Wf3 = (const float*)d_in[5];
  float* out = (float*)d_out;
  char* ws = (char*)d_ws;

  // Workspace (~40 MB). Zeroed pads below zA / y2b serve FIR/IIR negative-
  // row reads (nonzero-tap rows >= -99 in pad; deeper overshoot rows are
  // in-bounds, values unused). z4/z5/z6 reuse zA (z3 dead by then).
  double* Scum = (double*)(ws + 0);                   // double[100]
  double* Htab = (double*)(ws + 2048);                // double[102]
  float*  c1   = (float*)(ws + 4096);                 // float[4704]
  const size_t PADZ = 65536;                          // 655360 B zeros
  const size_t ZA   = PADZ + 655360;                  // 720896
  const size_t PADY = ZA + 13107200 + 262144;         // 14090240 (131072 zeros)
  const size_t Y2B  = PADY + 131072;                  // 14221312
  const size_t S1B  = Y2B + 2408448 + 65536;          // 16695296
  const size_t S2B  = S1B + 9633792;                  // 26329088
  const size_t S3B  = S2B + 2408448;                  // 28737536
  const size_t S4B  = S3B + 3276800;                  // 32014336
  const size_t S5B  = S4B + 614400;                   // 32628736
  const size_t WB   = S5B + 307200;                   // 32935936 WT2
  const size_t WC   = WB + 180000;                    // 33115936 WT3
  const size_t BLa  = 33122000;                       // BL: 6,881,280 (16-al.)
  const size_t BL2a = BLa + 6881280;                  // 40003280 (16-aligned)
  float* zA = (float*)(ws + ZA);
  unsigned char* y2b = (unsigned char*)(ws + Y2B);
  unsigned char* s1b = (unsigned char*)(ws + S1B);
  unsigned char* s2b = (unsigned char*)(ws + S2B);
  unsigned char* s3b = (unsigned char*)(ws + S3B);
  unsigned char* s4b = (unsigned char*)(ws + S4B);
  unsigned char* s5b = (unsigned char*)(ws + S5B);
  float* WT2 = (float*)(ws + WB);
  float* WT3 = (float*)(ws + WC);
  unsigned short* BLp  = (unsigned short*)(ws + BLa);
  unsigned short* BL2p = (unsigned short*)(ws + BL2a);  // 30,720 B

  // IIR coefficients (host, double): h[k] = c*k*b^k, truncated at K=100.
  double b = exp(-0.1), c = 0.1 * exp(1.0);
  double A1 = 2.0 * b, A2 = b * b;
  double B1 = c * b;
  double C0 = 100.0 * c * pow(b, 100.0);
  double C1 = 99.0 * c * pow(b, 101.0);
  double sc = (double)1.1f;                  // pool weight, exact fp32 value

  hipMemsetAsync(ws + PADZ, 0, 655360, stream);
  hipMemsetAsync(ws + PADY, 0, 131072, stream);
  k_prep<<<484, 256, 0, stream>>>(x, Wc1, Wc2, Wf1, Wf2, Wf3, c1, Scum, Htab,
                                  WT2, WT3, BLp, BL2p);
  k_scan1_chunk<<<NCHK * 4704 / 256, 256, 0, stream>>>(c1, Scum, s1b);
  k_pool<<<(1176 * T_BINS) / 256, 256, 0, stream>>>(s1b, y2b);
  k_psp_scan_chunk<unsigned char, unsigned char>
      <<<(NCHK * 1176 + 255) / 256, 256, 0, stream>>>(
      y2b, s2b, 1176, 1176L, 1L, Htab, A1, A2, B1 * sc, C0 * sc, C1 * sc, sc);
  k_conv2_mfma<<<T_BINS / 4, 256, 0, stream>>>(s2b, BL2p, zA);
  k_psp_scan_chunk<float, unsigned char>
      <<<(NCHK * 1600 + 255) / 256, 256, 0, stream>>>(
      zA, s3b, 1600, 1600L, 1L, Htab, A1, A2, B1, C0, C1, 1.0);
  k_mfma_dense1<<<256, 512, 0, stream>>>(s3b, BLp, zA);
  k_psp_scan_chunk<float, unsigned char>
      <<<(NCHK * 300 + 255) / 256, 256, 0, stream>>>(
      zA, s4b, 300, 300L, 1L, Htab, A1, A2, B1, C0, C1, 1.0);
  k_dense_sparse<300, 150, 192><<<T_BINS, 192, 0, stream>>>(s4b, WT2, zA);
  k_psp_scan_chunk<float, unsigned char>
      <<<(NCHK * 150 + 255) / 256, 256, 0, stream>>>(
      zA, s5b, 150, 150L, 1L, Htab, A1, A2, B1, C0, C1, 1.0);
  k_dense_sparse<150, 10, 64><<<T_BINS, 64, 0, stream>>>(s5b, WT3, zA);
  k_psp_scan_chunk<float, float>
      <<<(NCHK * 10 + 255) / 256, 256, 0, stream>>>(
      zA, out, 10, 1L, 2048L, Htab, A1, A2, B1, C0, C1, 1.0);

  (void)in_sizes; (void)n_in; (void)out_size; (void)ws_size;
}

// Round 25
// 197.608 us; speedup vs baseline: 1.0742x; 1.0062x over previous
//
#include <hip/hip_runtime.h>
#include <math.h>

// SLAYER SNN forward, 6 layers, T=2048.  (R25 = exact revert to the R21/R23
// best-measured configuration: 198.8 us, absmax 0. R24's WUP=32 FAILED --
// decision margins are not bounded by fp32 noise; near-threshold crossings
// flip under e^-32 perturbations and cascade. WUP=48 is the validated floor.)
//
// Policy: compute near the TRUE value (error << reference's own fp32 noise
// ~1e-5) so binary spike decisions match the golden fp32 reference exactly.
//
// PSP = exact 2nd-order IIR of the truncated SRM kernel; refractory = 2-state
// recurrence; time-chunked speculative scan (64 chunks x 32 steps, 48-step
// warmup -- WUP=48 proven R7-R23; chunks with t0<WUP start at ts=0 EXACTLY).
//
// DENSE1 (1600->300) and CONV2 as EXACT fixed-point bf16 MFMA:
//   w_fixed = round(w*2^45) = sum_{j<6} d_j 256^j, d_j signed 8-bit digits.
//   Digits and 0/1 spikes are exact in bf16; mfma_f32_16x16x32_bf16
//   accumulates integer partial sums -> EXACT in f32 C (< 2^24). Cross-wave
//   reduce (dense1) in F32 (8-way sums of exact ints -> exact), f64 limb
//   combine (terms integer x 2^(8j); residual ~1e-12 weight units).

#define T_BINS 2048
#define K_SRM  100
#define AEXP   0.36787944117144233   // e^-1
#define CHK    32                    // chunk output length
#define WUP    48                    // refractory warmup length (validated floor)
#define NCHK   (T_BINS / CHK)        // 64
#define FIXS   35184372088832.0      // 2^45
#define KSP    56                    // dense1 padded ks count (50 real + 6)

typedef __attribute__((ext_vector_type(8))) short          s16x8;
typedef __attribute__((ext_vector_type(8))) unsigned short u16x8;
typedef __attribute__((ext_vector_type(4))) float          f32x4;

// ---------------- fused prep: conv1 + packB + packB2 + transposes + init ----
__global__ __launch_bounds__(256) void k_prep(
    const float* __restrict__ x, const float* __restrict__ Wc1,
    const float* __restrict__ Wc2, const float* __restrict__ Wf1,
    const float* __restrict__ Wf2, const float* __restrict__ Wf3,
    float* __restrict__ c1, double* __restrict__ Scum, double* __restrict__ H,
    float* __restrict__ WT2, float* __restrict__ WT3,
    unsigned short* __restrict__ BL, unsigned short* __restrict__ BL2) {
  int b = blockIdx.x, tid = threadIdx.x;
  if (b < 19) {                         // ---- conv1 -> c1[4704]
    int idx = b * 256 + tid;
    if (idx >= 4704) return;
    int o = idx / 784, r = idx % 784, i = r / 28, j = r % 28;
    double acc = 0.0;
    for (int ci = 0; ci < 3; ++ci)
      for (int ky = 0; ky < 5; ++ky) {
        const float* xr = x + ci * 1024 + (i + ky) * 32 + j;
        const float* wr = Wc1 + ((o * 3 + ci) * 5 + ky) * 5;
#pragma unroll
        for (int kx = 0; kx < 5; ++kx)
          acc += (double)xr[kx] * (double)wr[kx];
      }
    c1[idx] = (float)acc;
  } else if (b < 299) {                 // ---- packB (dense1): 6 bf16 limbs
    int idx = (b - 19) * 256 + tid;     // 56 ks x 320 n x 4 g = 71680
    if (idx >= KSP * 320 * 4) return;
    int g = idx & 3, rest = idx >> 2;
    int n = rest % 320, ks = rest / 320;
    u16x8 out[6];
#pragma unroll
    for (int j = 0; j < 6; ++j)
#pragma unroll
      for (int jj = 0; jj < 8; ++jj) out[j][jj] = 0;
    if (n < 300 && ks < 50) {
      const float* wr = Wf1 + (size_t)n * 1600 + ks * 32 + g * 8;
#pragma unroll
      for (int jj = 0; jj < 8; ++jj) {
        long long v = llrint((double)wr[jj] * FIXS);
#pragma unroll
        for (int j = 0; j < 6; ++j) {
          int d = (int)(signed char)(v & 0xFF);
          v = (v - d) >> 8;
          float fd = (float)d;               // exact; bf16 truncation exact
          unsigned int fb = __float_as_uint(fd);
          out[j][jj] = (unsigned short)(fb >> 16);
        }
      }
    }
#pragma unroll
    for (int j = 0; j < 6; ++j)
      ((u16x8*)BL)[((j * KSP + ks) * 320 + n) * 4 + g] = out[j];
  } else if (b < 481) {                 // ---- WT2 / WT3 transposes
    int idx = (b - 299) * 256 + tid;
    if (idx < 45000) {
      int c = idx / 150, o = idx - c * 150;
      WT2[idx] = Wf2[o * 300 + c];
    } else if (idx < 46500) {
      int j = idx - 45000, c = j / 10, o = j - c * 10;
      WT3[j] = Wf3[o * 150 + c];
    }
  } else if (b < 483) {                 // ---- packB2 (conv2): 6 bf16 limbs
    int idx = (b - 481) * 256 + tid;    // 5 ks x 16 o x 4 g = 320
    if (idx >= 320) return;
    int g = idx & 3, rest = idx >> 2;
    int o = rest & 15, ks = rest >> 4;  // ks in 0..4
    u16x8 out[6];
#pragma unroll
    for (int j = 0; j < 6; ++j)
#pragma unroll
      for (int jj = 0; jj < 8; ++jj) out[j][jj] = 0;
#pragma unroll
    for (int jj = 0; jj < 8; ++jj) {
      int k = ks * 32 + g * 8 + jj;
      if (k < 150) {
        long long v = llrint((double)Wc2[o * 150 + k] * FIXS);
#pragma unroll
        for (int j = 0; j < 6; ++j) {
          int d = (int)(signed char)(v & 0xFF);
          v = (v - d) >> 8;
          float fd = (float)d;
          unsigned int fb = __float_as_uint(fd);
          out[j][jj] = (unsigned short)(fb >> 16);
        }
      }
    }
#pragma unroll
    for (int j = 0; j < 6; ++j)          // lane-contiguous layout: r fastest
      ((u16x8*)BL2)[((j * 5 + ks) * 4 + g) * 16 + o] = out[j];
  } else {                              // ---- init tables
    if (tid == 0) {
      double acc = 0.0;
      for (int k = 0; k < K_SRM; ++k) {
        double tk = (double)k;
        double h = (tk * 0.1) * exp(1.0 - tk * 0.1);
        H[k] = h; acc += h; Scum[k] = acc;
      }
      H[100] = 0.0; H[101] = 0.0;
    }
  }
}

// ---------------- layer1 chunked scan: p1[t] = c1*Scum[t] -------------------
__global__ __launch_bounds__(256) void k_scan1_chunk(
    const float* __restrict__ c1, const double* __restrict__ Scum_g,
    unsigned char* __restrict__ s1b) {
  __shared__ double Sc[K_SRM];
  for (int k = threadIdx.x; k < K_SRM; k += 256) Sc[k] = Scum_g[k];
  __syncthreads();
  int idx = blockIdx.x * 256 + threadIdx.x;
  int chunk = idx / 4704, n = idx - chunk * 4704;
  int t0 = chunk * CHK;
  int ts = t0 - WUP; if (ts < 0) ts = 0;   // ts==0 -> exact init
  double w = (double)c1[n];
  double e1 = 0.0, e2 = 0.0;
  double u = w * Sc[ts < (K_SRM - 1) ? ts : (K_SRM - 1)];
  unsigned char* outp = s1b + n;
  for (int t = ts; t < t0; ++t) {       // warmup, no store
    double s = (u >= 1.0) ? 1.0 : 0.0;
    int si = t + 1 < (K_SRM - 1) ? t + 1 : (K_SRM - 1);
    u = w * Sc[si] - 2.0 * ((e1 + e2) + s);
    double t1 = e1 + s;
    e2 = AEXP * (e2 + t1); e1 = AEXP * t1;
  }
#pragma unroll 8
  for (int t = t0; t < t0 + CHK; ++t) { // output
    double s = (u >= 1.0) ? 1.0 : 0.0;
    outp[(size_t)t * 4704] = (unsigned char)s;
    int si = t + 1 < (K_SRM - 1) ? t + 1 : (K_SRM - 1);
    u = w * Sc[si] - 2.0 * ((e1 + e2) + s);
    double t1 = e1 + s;
    e2 = AEXP * (e2 + t1); e1 = AEXP * t1;
  }
}

// ---------------- pool: 2x2 spike count -> y2b[t][1176] bytes ---------------
__global__ __launch_bounds__(256) void k_pool(const unsigned char* __restrict__ s1b,
                                              unsigned char* __restrict__ y2b) {
  int idx = blockIdx.x * blockDim.x + threadIdx.x;
  if (idx >= 1176 * T_BINS) return;
  int t = idx / 1176, n2 = idx - t * 1176;
  int c = n2 / 196, r = n2 % 196, i = r / 14, j = r % 14;
  const unsigned char* b = s1b + (size_t)t * 4704 + c * 784 + (2 * i) * 28 + 2 * j;
  y2b[idx] = (unsigned char)((int)b[0] + (int)b[1] + (int)b[28] + (int)b[29]);
}

// ---------------- chunked fused PSP(IIR) + spike scan -----------------------
template <typename Tin, typename Tout>
__global__ __launch_bounds__(256) void k_psp_scan_chunk(
    const Tin* __restrict__ z, Tout* __restrict__ sout, int N,
    long strideT, long strideN, const double* __restrict__ H_g,
    double A1, double A2, double B1, double C0, double C1, double xscale) {
  __shared__ double Hs[102];
  for (int k = threadIdx.x; k < 102; k += 256) Hs[k] = H_g[k];
  __syncthreads();
  int idx = blockIdx.x * blockDim.x + threadIdx.x;
  if (idx >= NCHK * N) return;
  int chunk = idx / N, n = idx - chunk * N;
  int t0 = chunk * CHK;
  int ts = t0 - WUP; if (ts < 0) ts = 0;   // ts==0 -> exact init
  const Tin* zn = z + n;

  // exact IIR init: accA=p[ts], accB=p[ts-1] (100-tap FIR, 10-deep pipe)
  double accA = 0.0, accB = 0.0;
  float fA[10], fB[10];
#define LOADF(BUF, J0)                                               \
  { _Pragma("unroll")                                                \
    for (int q_ = 0; q_ < 10; ++q_)                                  \
      BUF[q_] = (float)zn[(long)(ts - 1 - ((J0) + q_)) * (long)N]; }
#define FMA10(BUF, J0)                                               \
  { _Pragma("unroll")                                                \
    for (int q_ = 0; q_ < 10; ++q_) {                                \
      double v_ = (double)BUF[q_];                                   \
      accA += Hs[(J0) + q_ + 1] * v_;                                \
      accB += Hs[(J0) + q_] * v_;                                    \
    } }
  LOADF(fA, 0)
  for (int q = 0; q < 100; q += 20) {
    LOADF(fB, q + 10)
    FMA10(fA, q)
    LOADF(fA, q + 20)                  // q=80: overshoot, in-bounds, unused
    FMA10(fB, q + 10)
  }
#undef LOADF
#undef FMA10
  double pp1 = accA * xscale;          // p[ts]
  double pp2 = accB * xscale;          // p[ts-1]
  double xm100 = (double)(float)zn[(long)(ts - 100) * (long)N];
  double u = pp1, e1 = 0.0, e2 = 0.0;  // refractory zero (exact at ts==0)

  float cA[8], cB[8], lA[8], lB[8];
  size_t oa = (size_t)n * (size_t)strideN + (size_t)t0 * (size_t)strideT;
  int nwg = (t0 - ts) >> 3;            // 0, 4, or 6 warmup groups
  int ngrp = nwg + CHK / 8;            // 4, 8, or 10 (even)
#define PREF8(CBUF, LBUF, TB)                                        \
  { long tb_ = (long)(TB);                                           \
    _Pragma("unroll")                                                \
    for (int j_ = 0; j_ < 8; ++j_) {                                 \
      CBUF[j_] = (float)zn[(tb_ + j_) * (long)N];                    \
      LBUF[j_] = (float)zn[(tb_ + j_ - 99) * (long)N];               \
    } }
#define PROC8(CBUF, LBUF, DOSTORE)                                   \
  { _Pragma("unroll")                                                \
    for (int j_ = 0; j_ < 8; ++j_) {                                 \
      double s = (u >= 1.0) ? 1.0 : 0.0;                             \
      if (DOSTORE) { sout[oa] = (Tout)s; oa += (size_t)strideT; }    \
      double xt = (double)CBUF[j_], x99 = (double)LBUF[j_];          \
      double pn = A1 * pp1 - A2 * pp2 + B1 * xt - C0 * x99           \
                  + C1 * xm100;                                      \
      xm100 = x99;                                                   \
      u = pn - 2.0 * ((e1 + e2) + s);                                \
      double t1 = e1 + s;                                            \
      e2 = AEXP * (e2 + t1); e1 = AEXP * t1;                         \
      pp2 = pp1; pp1 = pn;                                           \
    } }
  PREF8(cA, lA, ts)
  for (int g = 0; g < ngrp; g += 2) {
    PREF8(cB, lB, ts + (g + 1) * 8)
    PROC8(cA, lA, g >= nwg)
    PREF8(cA, lA, ts + (g + 2) * 8)    // last iter overshoots into slack
    PROC8(cB, lB, g + 1 >= nwg)
  }
#undef PREF8
#undef PROC8
}

// ---------------- conv2 as exact bf16-limb MFMA -----------------------------
// 512 blocks x 256 thr (4 waves = 4 t). Per t: C[p][o], 7 m-tiles of 16,
// K=150 zero-padded to 160 (5 ks of 32), N=16 (one tile). B limbs (30KB) +
// spike rows + im2col offset table staged in LDS. A-fragments built from
// LDS bytes (predicated, static idx). Per-limb C exact (<150*128 < 2^24);
// f64 limb combine. D: col=lane&15 (o), row=(lane>>4)*4+q (p).
__global__ __launch_bounds__(256, 2) void k_conv2_mfma(
    const unsigned char* __restrict__ s2b, const unsigned short* __restrict__ BL2g,
    float* __restrict__ z3) {
  __shared__ __align__(16) unsigned short bl2[15360];  // 30,720 B
  __shared__ unsigned char ls[4][1216];                // 4,864 B
  __shared__ int tab[160];                             // 640 B
  int tid = threadIdx.x;
  for (int i = tid; i < 7680; i += 256)
    ((unsigned int*)bl2)[i] = ((const unsigned int*)BL2g)[i];
  if (tid < 160) {
    int k = tid;
    int ci = k / 25, rem = k - ci * 25;
    int ky = rem / 5, kx = rem - ky * 5;
    tab[k] = (k < 150) ? (ci * 196 + ky * 14 + kx) : 0;
  }
  int w = tid >> 6, lane = tid & 63;
  int t = blockIdx.x * 4 + w;
  {
    const unsigned int* srow = (const unsigned int*)(s2b + (size_t)t * 1176);
    unsigned int* dst = (unsigned int*)ls[w];
    for (int i = lane; i < 294; i += 64) dst[i] = srow[i];
  }
  __syncthreads();
  int r = lane & 15, g = lane >> 4;
#pragma unroll
  for (int mt = 0; mt < 7; ++mt) {
    int p = mt * 16 + r;
    int pi = p / 10;
    int pioff = pi * 14 + (p - pi * 10);
    s16x8 a[5];
#pragma unroll
    for (int ks = 0; ks < 5; ++ks) {
      u16x8 f;
#pragma unroll
      for (int jj = 0; jj < 8; ++jj) {
        int k = ks * 32 + g * 8 + jj;
        bool v = (mt < 6 || p < 100) && (ks < 4 || k < 150);
        int idx = v ? (tab[k] + pioff) : 0;
        unsigned char byte = ls[w][idx];
        f[jj] = (v && byte) ? (unsigned short)0x3F80 : (unsigned short)0;
      }
      a[ks] = (s16x8)f;
    }
    double zacc[4] = {0.0, 0.0, 0.0, 0.0};
    double scale = 1.0;
    for (int j = 0; j < 6; ++j) {
      f32x4 C = (f32x4){0.f, 0.f, 0.f, 0.f};
#pragma unroll
      for (int ks = 0; ks < 5; ++ks) {
        const u16x8* bf = (const u16x8*)bl2 + (((j * 5 + ks) * 4 + g) * 16 + r);
        C = __builtin_amdgcn_mfma_f32_16x16x32_bf16(a[ks], (s16x8)(*bf), C, 0, 0, 0);
      }
#pragma unroll
      for (int q = 0; q < 4; ++q) zacc[q] += scale * (double)C[q];
      scale *= 256.0;
    }
#pragma unroll
    for (int q = 0; q < 4; ++q) {
      int pr = mt * 16 + g * 4 + q;
      if (pr < 100)
        z3[(size_t)t * 1600 + r * 100 + pr] = (float)(zacc[q] * (1.0 / FIXS));
    }
  }
}

// ---------------- dense1 bf16-limb MFMA: M-blocked, single-phase reduce -----
// 256 blocks x 512 thr (8 waves): xcd=bid&7, ct=xcd&3 (one B-panel per XCD
// L2), bm=(bid>>3)|((xcd>>2)<<5) in 0..63 (32-row tile). Wave w owns ks
// [7w,7w+7) over zero-padded KSP=56; computes TWO 16-row subtiles with each
// B fragment. ONE reduce phase per limb via redf[8][64][41] (82KB LDS).
__global__ __launch_bounds__(512, 2) void k_mfma_dense1(
    const unsigned char* __restrict__ s3b, const unsigned short* __restrict__ BL,
    float* __restrict__ z4) {
  __shared__ float redf[8][64][41];     // 83,968 B
  int bid = blockIdx.x;
  int xcd = bid & 7;
  int ct = xcd & 3;
  int bm = (bid >> 3) | ((xcd >> 2) << 5);     // 0..63
  int col0 = ct * 80;
  int w = threadIdx.x >> 6, lane = threadIdx.x & 63;
  int r = lane & 15, g = lane >> 4;
  int ks0 = w * 7;
  int rowA = bm * 32 + r, rowB = rowA + 16;
  const unsigned char* abA = s3b + (size_t)rowA * 1600 + ks0 * 32 + g * 8;
  const unsigned char* abB = s3b + (size_t)rowB * 1600 + ks0 * 32 + g * 8;

  // hoist A fragments for both subtiles (static unroll, rule #20)
  s16x8 aA[7], aB[7];
#pragma unroll
  for (int ks = 0; ks < 7; ++ks) {
    unsigned long long bA = *(const unsigned long long*)(abA + ks * 32);
    unsigned long long bB = *(const unsigned long long*)(abB + ks * 32);
    u16x8 fa, fb;
#pragma unroll
    for (int jj = 0; jj < 8; ++jj) {
      fa[jj] = ((bA >> (8 * jj)) & 1ULL) ? (unsigned short)0x3F80
                                         : (unsigned short)0;
      fb[jj] = ((bB >> (8 * jj)) & 1ULL) ? (unsigned short)0x3F80
                                         : (unsigned short)0;
    }
    aA[ks] = (s16x8)fa; aB[ks] = (s16x8)fb;
  }

  double zawA[4] = {0.0, 0.0, 0.0, 0.0};  // waves w<5 accumulate (nt = w)
  double zawB[4] = {0.0, 0.0, 0.0, 0.0};
  double scale = 1.0;
  for (int j = 0; j < 6; ++j) {
    f32x4 CA[5], CB[5];
#pragma unroll
    for (int nt = 0; nt < 5; ++nt) {
      CA[nt] = (f32x4){0.f, 0.f, 0.f, 0.f};
      CB[nt] = (f32x4){0.f, 0.f, 0.f, 0.f};
    }
#pragma unroll
    for (int ks = 0; ks < 7; ++ks) {   // branch-free, fully static
      const u16x8* bb =
          (const u16x8*)BL + ((size_t)((j * KSP + ks0 + ks) * 320 + col0 + r)) * 4 + g;
#pragma unroll
      for (int nt = 0; nt < 5; ++nt) {
        s16x8 bf = (s16x8)bb[nt * 64];
        CA[nt] = __builtin_amdgcn_mfma_f32_16x16x32_bf16(aA[ks], bf, CA[nt], 0, 0, 0);
        CB[nt] = __builtin_amdgcn_mfma_f32_16x16x32_bf16(aB[ks], bf, CB[nt], 0, 0, 0);
      }
    }
    // ---- single-phase reduce: CA -> 0..19, CB -> 20..39
#pragma unroll
    for (int nt = 0; nt < 5; ++nt)
#pragma unroll
      for (int q = 0; q < 4; ++q) {
        redf[w][lane][nt * 4 + q]      = CA[nt][q];
        redf[w][lane][20 + nt * 4 + q] = CB[nt][q];
      }
    __syncthreads();
    if (w < 5) {
#pragma unroll
      for (int q = 0; q < 4; ++q) {
        int i = w * 4 + q;
        float sA = ((redf[0][lane][i] + redf[1][lane][i]) +
                    (redf[2][lane][i] + redf[3][lane][i])) +
                   ((redf[4][lane][i] + redf[5][lane][i]) +
                    (redf[6][lane][i] + redf[7][lane][i]));
        int i2 = 20 + i;
        float sB = ((redf[0][lane][i2] + redf[1][lane][i2]) +
                    (redf[2][lane][i2] + redf[3][lane][i2])) +
                   ((redf[4][lane][i2] + redf[5][lane][i2]) +
                    (redf[6][lane][i2] + redf[7][lane][i2]));
        zawA[q] += scale * (double)sA;
        zawB[q] += scale * (double)sB;
      }
    }
    __syncthreads();
    scale *= 256.0;
  }

  if (w < 5) {
    int col = col0 + w * 16 + r;       // nt = w
    if (col < 300) {
      int rA0 = bm * 32 + g * 4, rB0 = rA0 + 16;
#pragma unroll
      for (int q = 0; q < 4; ++q) {
        z4[(size_t)(rA0 + q) * 300 + col] = (float)(zawA[q] * (1.0 / FIXS));
        z4[(size_t)(rB0 + q) * 300 + col] = (float)(zawB[q] * (1.0 / FIXS));
      }
    }
  }
}

// ---------------- sparse dense: one output per lane -------------------------
template <int NIN, int NOUT, int BLK>
__global__ __launch_bounds__(BLK) void k_dense_sparse(
    const unsigned char* __restrict__ s, const float* __restrict__ WT,
    float* __restrict__ z) {
  constexpr int NCH = (NIN + BLK - 1) / BLK;
  constexpr int NW = BLK / 64;
  __shared__ __align__(16) int list[NIN];
  __shared__ int wcnt[NCH][NW];
  int t = blockIdx.x;
  const unsigned char* srow = s + (size_t)t * NIN;
  int tid = threadIdx.x, lane = tid & 63, wv = tid >> 6;
  unsigned long long msave[NCH];
  bool asave[NCH];
#pragma unroll
  for (int ci = 0; ci < NCH; ++ci) {
    int c = ci * BLK + tid;
    bool a = (c < NIN) && (srow[c] != 0);
    unsigned long long m = __ballot(a);
    msave[ci] = m; asave[ci] = a;
    if (lane == 0) wcnt[ci][wv] = __popcll(m);
  }
  __syncthreads();
  int nact = 0;
#pragma unroll
  for (int ci = 0; ci < NCH; ++ci) {
    int off = nact;
    for (int w = 0; w < wv; ++w) off += wcnt[ci][w];
    if (asave[ci])
      list[off + __popcll(msave[ci] & ((1ULL << lane) - 1))] = ci * BLK + tid;
    for (int w = 0; w < NW; ++w) nact += wcnt[ci][w];
  }
  __syncthreads();
  if (tid >= NOUT) return;
  const float* col = WT + tid;
  double a0 = 0.0, a1 = 0.0, a2 = 0.0, a3 = 0.0;
  int k = 0, nact4 = nact & ~3;
  for (; k < nact4; k += 4) {
    int4 l4 = *(const int4*)&list[k];
    a0 += (double)col[(size_t)l4.x * NOUT];
    a1 += (double)col[(size_t)l4.y * NOUT];
    a2 += (double)col[(size_t)l4.z * NOUT];
    a3 += (double)col[(size_t)l4.w * NOUT];
  }
  for (; k < nact; ++k) a0 += (double)col[(size_t)list[k] * NOUT];
  z[(size_t)t * NOUT + tid] = (float)((a0 + a1) + (a2 + a3));
}

// ---------------- launch ----------------------------------------------------
extern "C" void kernel_launch(void* const* d_in, const int* in_sizes, int n_in,
                              void* d_out, int out_size, void* d_ws, size_t ws_size,
                              hipStream_t stream) {
  const float* x   = (const float*)d_in[0];
  const float* Wc1 = (const float*)d_in[1];
  const float* Wc2 = (const float*)d_in[2];
  const float* Wf1 = (const float*)d_in[3];
  const float* Wf2 = (const float*)d_in[4];
  const float* Wf3 = (const float*)d_in[5];
  float* out = (float*)d_out;
  char* ws = (char*)d_ws;

  // Workspace (~40 MB). Zeroed pads below zA / y2b serve FIR/IIR negative-
  // row reads (nonzero-tap rows >= -99 in pad; deeper overshoot rows are
  // in-bounds, values unused). z4/z5/z6 reuse zA (z3 dead by then).
  double* Scum = (double*)(ws + 0);                   // double[100]
  double* Htab = (double*)(ws + 2048);                // double[102]
  float*  c1   = (float*)(ws + 4096);                 // float[4704]
  const size_t PADZ = 65536;                          // 655360 B zeros
  const size_t ZA   = PADZ + 655360;                  // 720896
  const size_t PADY = ZA + 13107200 + 262144;         // 14090240 (131072 zeros)
  const size_t Y2B  = PADY + 131072;                  // 14221312
  const size_t S1B  = Y2B + 2408448 + 65536;          // 16695296
  const size_t S2B  = S1B + 9633792;                  // 26329088
  const size_t S3B  = S2B + 2408448;                  // 28737536
  const size_t S4B  = S3B + 3276800;                  // 32014336
  const size_t S5B  = S4B + 614400;                   // 32628736
  const size_t WB   = S5B + 307200;                   // 32935936 WT2
  const size_t WC   = WB + 180000;                    // 33115936 WT3
  const size_t BLa  = 33122000;                       // BL: 6,881,280 (16-al.)
  const size_t BL2a = BLa + 6881280;                  // 40003280 (16-aligned)
  float* zA = (float*)(ws + ZA);
  unsigned char* y2b = (unsigned char*)(ws + Y2B);
  unsigned char* s1b = (unsigned char*)(ws + S1B);
  unsigned char* s2b = (unsigned char*)(ws + S2B);
  unsigned char* s3b = (unsigned char*)(ws + S3B);
  unsigned char* s4b = (unsigned char*)(ws + S4B);
  unsigned char* s5b = (unsigned char*)(ws + S5B);
  float* WT2 = (float*)(ws + WB);
  float* WT3 = (float*)(ws + WC);
  unsigned short* BLp  = (unsigned short*)(ws + BLa);
  unsigned short* BL2p = (unsigned short*)(ws + BL2a);  // 30,720 B

  // IIR coefficients (host, double): h[k] = c*k*b^k, truncated at K=100.
  double b = exp(-0.1), c = 0.1 * exp(1.0);
  double A1 = 2.0 * b, A2 = b * b;
  double B1 = c * b;
  double C0 = 100.0 * c * pow(b, 100.0);
  double C1 = 99.0 * c * pow(b, 101.0);
  double sc = (double)1.1f;                  // pool weight, exact fp32 value

  hipMemsetAsync(ws + PADZ, 0, 655360, stream);
  hipMemsetAsync(ws + PADY, 0, 131072, stream);
  k_prep<<<484, 256, 0, stream>>>(x, Wc1, Wc2, Wf1, Wf2, Wf3, c1, Scum, Htab,
                                  WT2, WT3, BLp, BL2p);
  k_scan1_chunk<<<NCHK * 4704 / 256, 256, 0, stream>>>(c1, Scum, s1b);
  k_pool<<<(1176 * T_BINS) / 256, 256, 0, stream>>>(s1b, y2b);
  k_psp_scan_chunk<unsigned char, unsigned char>
      <<<(NCHK * 1176 + 255) / 256, 256, 0, stream>>>(
      y2b, s2b, 1176, 1176L, 1L, Htab, A1, A2, B1 * sc, C0 * sc, C1 * sc, sc);
  k_conv2_mfma<<<T_BINS / 4, 256, 0, stream>>>(s2b, BL2p, zA);
  k_psp_scan_chunk<float, unsigned char>
      <<<(NCHK * 1600 + 255) / 256, 256, 0, stream>>>(
      zA, s3b, 1600, 1600L, 1L, Htab, A1, A2, B1, C0, C1, 1.0);
  k_mfma_dense1<<<256, 512, 0, stream>>>(s3b, BLp, zA);
  k_psp_scan_chunk<float, unsigned char>
      <<<(NCHK * 300 + 255) / 256, 256, 0, stream>>>(
      zA, s4b, 300, 300L, 1L, Htab, A1, A2, B1, C0, C1, 1.0);
  k_dense_sparse<300, 150, 192><<<T_BINS, 192, 0, stream>>>(s4b, WT2, zA);
  k_psp_scan_chunk<float, unsigned char>
      <<<(NCHK * 150 + 255) / 256, 256, 0, stream>>>(
      zA, s5b, 150, 150L, 1L, Htab, A1, A2, B1, C0, C1, 1.0);
  k_dense_sparse<150, 10, 64><<<T_BINS, 64, 0, stream>>>(s5b, WT3, zA);
  k_psp_scan_chunk<float, float>
      <<<(NCHK * 10 + 255) / 256, 256, 0, stream>>>(
      zA, out, 10, 1L, 2048L, Htab, A1, A2, B1, C0, C1, 1.0);

  (void)in_sizes; (void)n_in; (void)out_size; (void)ws_size;
}